// Round 17
// baseline (380.587 us; speedup 1.0000x reference)
//
#include <hip/hip_runtime.h>

#define DD 64
#define CHUNK_A 4096            // edges per partition block
#define SRC_MASK 0x1FFFF        // 17 bits: N = 50000 < 131072

typedef float f32x4 __attribute__((ext_vector_type(4)));

// ---- kernel 1: dual per-block bucket counts (dst>>8 and src>>8) ----
__global__ __launch_bounds__(256) void k_pre(const int* __restrict__ src,
                                             const int* __restrict__ dst,
                                             int* __restrict__ M,
                                             int* __restrict__ Msrc, int E) {
    __shared__ int hd[256], hs[256];
    int t = threadIdx.x;
    int bid = blockIdx.x;
    hd[t] = 0; hs[t] = 0;
    __syncthreads();
    int base = bid * CHUNK_A;
#pragma unroll
    for (int k = 0; k < CHUNK_A / 256; ++k) {
        int e = base + t + (k << 8);
        if (e < E) {
            atomicAdd(&hd[dst[e] >> 8], 1);
            atomicAdd(&hs[src[e] >> 8], 1);
        }
    }
    __syncthreads();
    M[bid * 256 + t] = hd[t];
    Msrc[bid * 256 + t] = hs[t];
}

// ---- kernel 2: two blocks, each scans one bucket matrix ----
__global__ __launch_bounds__(256) void k_binscan(int* __restrict__ M,
                                                 int* __restrict__ Msrc,
                                                 int* __restrict__ binBase,
                                                 int* __restrict__ binBaseS,
                                                 int* __restrict__ rstart,
                                                 int PB, int n, int E) {
    int t = threadIdx.x;
    int* Mx = (blockIdx.x == 0) ? M : Msrc;
    int* bb = (blockIdx.x == 0) ? binBase : binBaseS;
    int tot = 0;
    for (int p = 0; p < PB; ++p) tot += Mx[p * 256 + t];
    int lane = t & 63, w = t >> 6;
    int inc = tot;
    for (int o = 1; o < 64; o <<= 1) {
        int u = __shfl_up(inc, o);
        if (lane >= o) inc += u;
    }
    __shared__ int wtot[4];
    if (lane == 63) wtot[w] = inc;
    __syncthreads();
    int woff = 0;
    for (int i = 0; i < w; ++i) woff += wtot[i];
    int base = woff + inc - tot;
    bb[t] = base;
    if (t == 255) bb[256] = base + tot;
    if (blockIdx.x == 0 && t == 0) rstart[n] = E;
    int run = base;
#pragma unroll 4
    for (int p = 0; p < PB; ++p) {
        int v = Mx[p * 256 + t];
        Mx[p * 256 + t] = run;
        run += v;
    }
}

// ---- kernel 3: dual scatter, LDS cursors ----
__global__ __launch_bounds__(256) void k_scatterA(const int* __restrict__ src,
                                                  const int* __restrict__ dst,
                                                  const int* __restrict__ ef,
                                                  const int* __restrict__ M,
                                                  const int* __restrict__ Msrc,
                                                  int* __restrict__ bucketA,
                                                  unsigned char* __restrict__ bucketS,
                                                  int E) {
    __shared__ int curD[256], curS[256];
    int t = threadIdx.x;
    int p = blockIdx.x;
    curD[t] = M[p * 256 + t];
    curS[t] = Msrc[p * 256 + t];
    __syncthreads();
    int base = p * CHUNK_A;
#pragma unroll
    for (int k = 0; k < CHUNK_A / 256; ++k) {
        int e = base + t + (k << 8);
        if (e < E) {
            int s = src[e], d = dst[e];
            int posD = atomicAdd(&curD[d >> 8], 1);
            bucketA[posD] = s | ((ef[e] & 1) << 17) | ((d & 255) << 18);
            int posS = atomicAdd(&curS[s >> 8], 1);
            bucketS[posS] = (unsigned char)(s & 255);
        }
    }
}

// ---- kernel 4: dst grouping -> edges+rstart+iinv; src counts -> oinv ----
__global__ __launch_bounds__(256) void k_bucket(const int* __restrict__ bucketA,
                                                const unsigned char* __restrict__ bucketS,
                                                const int* __restrict__ binBase,
                                                const int* __restrict__ binBaseS,
                                                int* __restrict__ rstart,
                                                float* __restrict__ iinv,
                                                float* __restrict__ oinv,
                                                int* __restrict__ edges, int n, int NB) {
    __shared__ int cnt[256];
    __shared__ int off[256];
    __shared__ int wtot[4];
    int t = threadIdx.x;
    int b = blockIdx.x;
    if (b < NB) {
        int s0 = binBase[b], s1 = binBase[b + 1];
        cnt[t] = 0;
        __syncthreads();
        for (int i = s0 + t; i < s1; i += 256)
            atomicAdd(&cnt[(bucketA[i] >> 18) & 255], 1);
        __syncthreads();
        int c = cnt[t];
        int lane = t & 63, w = t >> 6;
        int inc = c;
        for (int o = 1; o < 64; o <<= 1) {
            int u = __shfl_up(inc, o);
            if (lane >= o) inc += u;
        }
        if (lane == 63) wtot[w] = inc;
        __syncthreads();
        int woff = 0;
        for (int i = 0; i < w; ++i) woff += wtot[i];
        int excl = woff + inc - c;
        int v = b * 256 + t;
        if (v < n) {
            rstart[v] = s0 + excl;
            iinv[v] = rsqrtf((float)max(c, 1));
        }
        off[t] = excl;
        __syncthreads();
        for (int i = s0 + t; i < s1; i += 256) {
            int r = bucketA[i];
            int cc = (r >> 18) & 255;
            int pos = atomicAdd(&off[cc], 1);
            edges[s0 + pos] = (r & SRC_MASK) | (int)(((unsigned)((r >> 17) & 1)) << 31);
        }
    } else {
        int bs = b - NB;
        int s0 = binBaseS[bs], s1 = binBaseS[bs + 1];
        cnt[t] = 0;
        __syncthreads();
        for (int i = s0 + t; i < s1; i += 256)
            atomicAdd(&cnt[(int)bucketS[i]], 1);
        __syncthreads();
        int v = bs * 256 + t;
        if (v < n) oinv[v] = rsqrtf((float)max(cnt[t], 1));
    }
}

// ---- transpose + oinv prescale: x [N,64] -> xq [4][N][16] ----
__global__ __launch_bounds__(256) void k_xpose(const f32x4* __restrict__ x4,
                                               const float* __restrict__ oinv,
                                               f32x4* __restrict__ xq4, int n) {
    int tid = blockIdx.x * 256 + threadIdx.x;
    if (tid >= n * 16) return;
    int v = tid >> 4, c = tid & 15;
    int q = c >> 2, cl = c & 3;
    f32x4 val = __builtin_nontemporal_load(&x4[tid]);
    float s = oinv[v];
    val *= s;
    __builtin_nontemporal_store(val, &xq4[((size_t)q * n + v) * 4 + cl]);
}

// ---- quarter-split gather: grid (ceil(n/4), 4); wave = (node v, quarter q) ----
// 16 edge slots x 4 lanes (float4 = 16 of 64 features). Quarter region = 3.2 MB -> L2-resident.
// MODE 0: input pre-scaled by oinv[src]; post=iinv*oinv; quarter-major out
// MODE 1: post=iinv; quarter-major out
// MODE 2: scale=parity?1:2; post=1; row-major out
template <int MODE>
__global__ __launch_bounds__(256) void k_gatherq(const float* __restrict__ xq,
                                                 const int* __restrict__ edges,
                                                 const int* __restrict__ rstart,
                                                 const float* __restrict__ oinv,
                                                 const float* __restrict__ iinv,
                                                 float* __restrict__ y, int n) {
    int v = blockIdx.x * 4 + (threadIdx.x >> 6);
    if (v >= n) return;
    int q = blockIdx.y;
    int lane = threadIdx.x & 63;
    int slot = lane >> 2;       // 0..15 edge slots
    int cl = lane & 3;          // float4 chunk within the 16-float quarter
    int s0 = rstart[v], s1 = rstart[v + 1];
    const float* xb = xq + (size_t)q * n * 16;
    float ax = 0.f, ay = 0.f, az = 0.f, aw = 0.f;
    for (int i = s0 + slot; i < s1; i += 16) {
        int rec = __builtin_nontemporal_load(&edges[i]);
        int s = rec & SRC_MASK;
        const float4 val = *(const float4*)(xb + s * 16 + cl * 4);
        float sc = 1.0f;
        if (MODE == 2) sc = (rec < 0) ? 1.0f : 2.0f;
        ax = fmaf(val.x, sc, ax); ay = fmaf(val.y, sc, ay);
        az = fmaf(val.z, sc, az); aw = fmaf(val.w, sc, aw);
    }
#pragma unroll
    for (int o = 4; o < 64; o <<= 1) {
        ax += __shfl_xor(ax, o); ay += __shfl_xor(ay, o);
        az += __shfl_xor(az, o); aw += __shfl_xor(aw, o);
    }
    if (slot == 0) {
        float post = 1.0f;
        if (MODE == 0) post = iinv[v] * oinv[v];
        if (MODE == 1) post = iinv[v];
        f32x4 o;
        o.x = ax * post; o.y = ay * post; o.z = az * post; o.w = aw * post;
        if (MODE == 2)
            __builtin_nontemporal_store(o, (f32x4*)(y + (size_t)v * DD + q * 16 + cl * 4));
        else
            __builtin_nontemporal_store(o, (f32x4*)(y + ((size_t)q * n + v) * 16 + cl * 4));
    }
}

// ---- dense GEMM on quarter-major: h1q = aggq @ W + b ----
__global__ __launch_bounds__(256) void k_gemm_q(const float* __restrict__ aggq,
                                                const float* __restrict__ W,
                                                const float* __restrict__ bias,
                                                float* __restrict__ h1q, int n) {
    __shared__ float Wl[64 * 64];
    __shared__ float rows[32][64];
    __shared__ float bl[64];
    int tid = threadIdx.x;
    const f32x4* W4 = (const f32x4*)W;
    f32x4* Wl4 = (f32x4*)Wl;
#pragma unroll
    for (int k = 0; k < 4; ++k) Wl4[tid + k * 256] = W4[tid + k * 256];
    if (tid < 64) bl[tid] = bias[tid];
    int r0 = blockIdx.x * 32;
    const f32x4* a4 = (const f32x4*)aggq;
#pragma unroll
    for (int j = tid; j < 512; j += 256) {
        int q = j >> 7, rem = j & 127, r = rem >> 2, cl = rem & 3;
        int gr = r0 + r;
        f32x4 val = {0.f, 0.f, 0.f, 0.f};
        if (gr < n) val = __builtin_nontemporal_load(&a4[((size_t)q * n + gr) * 4 + cl]);
        *(f32x4*)&rows[r][q * 16 + cl * 4] = val;
    }
    __syncthreads();
    int col = tid & 63;
    int rg = tid >> 6;
    float bc = bl[col];
    int qc = col >> 4, clc = col & 15;
    for (int rr = 0; rr < 8; ++rr) {
        int r = rg * 8 + rr;
        int gr = r0 + r;
        if (gr >= n) break;
        float acc = bc;
#pragma unroll
        for (int k = 0; k < 64; ++k) acc = fmaf(rows[r][k], Wl[k * 64 + col], acc);
        __builtin_nontemporal_store(acc, &h1q[((size_t)qc * n + gr) * 16 + clc]);
    }
}

extern "C" void kernel_launch(void* const* d_in, const int* in_sizes, int n_in,
                              void* d_out, int out_size, void* d_ws, size_t ws_size,
                              hipStream_t stream) {
    const float* x   = (const float*)d_in[0];
    const float* W   = (const float*)d_in[1];
    const float* b   = (const float*)d_in[2];
    const int*   src = (const int*)d_in[3];
    const int*   dst = (const int*)d_in[4];
    const int*   ef  = (const int*)d_in[5];
    float* out = (float*)d_out;

    const int n = in_sizes[0] / DD;
    const int E = in_sizes[3];

    const int PB = (E + CHUNK_A - 1) / CHUNK_A;      // partition blocks
    const int NB = (n + 255) >> 8;                   // coarse buckets

    char* ws = (char*)d_ws;
    size_t np = ((size_t)n + 255) & ~(size_t)255;
    float* oinv    = (float*)ws; ws += np * 4;
    float* iinv    = (float*)ws; ws += np * 4;
    int*   rstart  = (int*)ws;   ws += (np + 256) * 4;
    int*   binBase = (int*)ws;   ws += 260 * 4;
    int*   binBaseS= (int*)ws;   ws += 260 * 4;
    int*   M       = (int*)ws;   ws += (size_t)PB * 256 * 4;
    int*   Msrc    = (int*)ws;   ws += (size_t)PB * 256 * 4;
    int*   bucketA = (int*)ws;   ws += (size_t)E * 4;
    unsigned char* bucketS = (unsigned char*)ws; ws += ((size_t)E + 255) & ~(size_t)255;
    int*   edges   = (int*)ws;   ws += (size_t)E * 4;
    size_t fbytes = (size_t)n * DD * sizeof(float);
    float* xq   = (float*)ws;    ws += fbytes;   // [4][N][16]; reused as h1q after g0
    float* h0q  = (float*)ws;    ws += fbytes;   // [4][N][16]
    float* aggq = (float*)ws;    ws += fbytes;   // [4][N][16]
    float* h1q  = xq;                            // alias: xq dead after gather-0

    k_pre<<<PB, 256, 0, stream>>>(src, dst, M, Msrc, E);
    k_binscan<<<2, 256, 0, stream>>>(M, Msrc, binBase, binBaseS, rstart, PB, n, E);
    k_scatterA<<<PB, 256, 0, stream>>>(src, dst, ef, M, Msrc, bucketA, bucketS, E);
    k_bucket<<<2 * NB, 256, 0, stream>>>(bucketA, bucketS, binBase, binBaseS,
                                         rstart, iinv, oinv, edges, n, NB);

    k_xpose<<<(n * 16 + 255) / 256, 256, 0, stream>>>((const f32x4*)x, oinv,
                                                      (f32x4*)xq, n);

    dim3 ggrid((n + 3) / 4, 4);
    k_gatherq<0><<<ggrid, 256, 0, stream>>>(xq, edges, rstart, oinv, iinv, h0q, n);
    k_gatherq<1><<<ggrid, 256, 0, stream>>>(h0q, edges, rstart, oinv, iinv, aggq, n);
    k_gemm_q<<<(n + 31) / 32, 256, 0, stream>>>(aggq, W, b, h1q, n);
    k_gatherq<2><<<ggrid, 256, 0, stream>>>(h1q, edges, rstart, oinv, iinv, out, n);
}